// Round 6
// baseline (192.199 us; speedup 1.0000x reference)
//
#include <hip/hip_runtime.h>
#include <hip/hip_bf16.h>

typedef unsigned short u16;
typedef unsigned int   u32;
using short8   = __attribute__((ext_vector_type(8))) short;
using f32x4    = __attribute__((ext_vector_type(4))) float;
using ushort4v = __attribute__((ext_vector_type(4))) unsigned short;
using u32x4    = __attribute__((ext_vector_type(4))) unsigned int;

#define LDIM 16384
#define LT   64
#define NT   256   // L tiles per batch
#define NB   8

__device__ __forceinline__ u16 f2bf(float f) {
  u32 u = __float_as_uint(f);
  u = (u + 0x7FFFu + ((u >> 16) & 1u)) >> 16;   // RTNE
  return (u16)u;
}
__device__ __forceinline__ float bf2f(u16 h) {
  return __uint_as_float((u32)h << 16);
}
__device__ __forceinline__ u32 pk2(float a, float b) {
  __hip_bfloat162 h = __float22bfloat162_rn(make_float2(a, b));  // a -> low
  return *(u32*)&h;
}

// LDS/q-image layout: byte(l,c) = l*512 + slot*16 + (c&7)*2,
//   slot = (c>>3) ^ swz(l),  swz(l) = ((l>>2)&31) ^ ((l&3)<<2)
__device__ __forceinline__ int swz(int l) {
  return ((l >> 2) & 31) ^ ((l & 3) << 2);
}
__device__ __forceinline__ short8 frag_b(const char* xl, int ll, int kk, int g) {
  int slot = (kk * 4 + g) ^ swz(ll);
  return *(const short8*)(xl + (size_t)ll * 512 + slot * 16);
}

// ---------------- prep: weight bf16, wvsum, bilinear upsample ----------------
__global__ void k_prep(const float* __restrict__ wq_x, const float* __restrict__ wk_x,
                       const float* __restrict__ wv, const float* __restrict__ y,
                       u16* __restrict__ wqx_bf, u16* __restrict__ wkx_bf,
                       u16* __restrict__ wvsum_bf, float* __restrict__ yup) {
  int id = blockIdx.x * 256 + threadIdx.x;
  if (id < 65536) {
    wqx_bf[id] = f2bf(wq_x[id]);
    wkx_bf[id] = f2bf(wk_x[id]);
  }
  if (id < 4096) {  // wvsum padded to 16 rows (rows 8..15 zero)
    int r = id >> 8, c = id & 255;
    float s = 0.f;
    if (r < 8) {
      for (int d2 = 0; d2 < 32; ++d2) s += wv[(r * 32 + d2) * 256 + c];
    }
    wvsum_bf[id] = f2bf(s);
  }
  if (id < 131072) {  // bilinear 2x upsample, half-pixel (align_corners=False)
    int b = id >> 14, rem = id & 16383, i = rem >> 7, j = rem & 127;
    float si = 0.5f * i - 0.25f, sj = 0.5f * j - 0.25f;
    int i0 = (int)floorf(si), j0 = (int)floorf(sj);
    float fi = si - (float)i0, fj = sj - (float)j0;
    int i0c = i0 < 0 ? 0 : i0, i1c = i0 + 1 > 63 ? 63 : i0 + 1;
    int j0c = j0 < 0 ? 0 : j0, j1c = j0 + 1 > 63 ? 63 : j0 + 1;
    const float* yb = y + b * 4096;
    float v = (1.f - fi) * ((1.f - fj) * yb[i0c * 64 + j0c] + fj * yb[i0c * 64 + j1c])
            +        fi  * ((1.f - fj) * yb[i1c * 64 + j0c] + fj * yb[i1c * 64 + j1c]);
    yup[id] = v;
  }
}

// ---------------- staging: x f32 -> swizzled LDS bf16 image (LT=64) ----------
__device__ __forceinline__ void stage_one_octet(char* xl, const float* p, int so, int k) {
  float4 r0 = *(const float4*)(p + 0 * LDIM);
  float4 r1 = *(const float4*)(p + 1 * LDIM);
  float4 r2 = *(const float4*)(p + 2 * LDIM);
  float4 r3 = *(const float4*)(p + 3 * LDIM);
  float4 r4 = *(const float4*)(p + 4 * LDIM);
  float4 r5 = *(const float4*)(p + 5 * LDIM);
  float4 r6 = *(const float4*)(p + 6 * LDIM);
  float4 r7 = *(const float4*)(p + 7 * LDIM);
  const float* f0 = (const float*)&r0; const float* f1 = (const float*)&r1;
  const float* f2 = (const float*)&r2; const float* f3 = (const float*)&r3;
  const float* f4 = (const float*)&r4; const float* f5 = (const float*)&r5;
  const float* f6 = (const float*)&r6; const float* f7 = (const float*)&r7;
#pragma unroll
  for (int e = 0; e < 4; ++e) {
    int l = k * 4 + e;
    u32x4 wv;
    wv.x = pk2(f0[e], f1[e]);
    wv.y = pk2(f2[e], f3[e]);
    wv.z = pk2(f4[e], f5[e]);
    wv.w = pk2(f6[e], f7[e]);
    int slot = so ^ swz(l);
    *(u32x4*)(xl + (size_t)l * 512 + slot * 16) = wv;
  }
}

__device__ __forceinline__ void stage_x(char* xl, const float* __restrict__ x,
                                        int b, int l0, int tid) {
  int k = tid & 15, cog = tid >> 4;   // l-quad (4 l's), base c-octet (0..15)
  const float* bp = x + ((size_t)b * 256 + cog * 8) * LDIM + l0 + k * 4;
#pragma unroll 1
  for (int oi = 0; oi < 2; ++oi)
    stage_one_octet(xl, bp + (size_t)(oi * 128) * LDIM, cog + oi * 16, k);
}

// ---------------- pass 1: k/q GEMMs, partials, q-image dump ------------------
__global__ __launch_bounds__(256, 2) void k_pass1(
    const float* __restrict__ x, const u16* __restrict__ wkx_bf,
    const u16* __restrict__ wqx_bf, const u16* __restrict__ wvsum_bf,
    const float* __restrict__ wk_y, const float* __restrict__ wq_y,
    const float* __restrict__ yup, u16* __restrict__ qimg,
    float* __restrict__ part) {
  __shared__ u32x4 xbuf[2048];            // 32 KB
  __shared__ float vsum_lds[8 * 64];
  __shared__ float yup_lds[64];
  __shared__ float wky_lds[256];
  __shared__ float wqy_lds[256];
  char* xl = (char*)xbuf;

  int tid = threadIdx.x, bid = blockIdx.x;
  int b = bid >> 8, tile = bid & 255;
  int l0 = tile * LT;

  if (tid < 64) yup_lds[tid] = yup[b * LDIM + l0 + tid];
  wky_lds[tid] = wk_y[tid];
  wqy_lds[tid] = wq_y[tid];
  stage_x(xl, x, b, l0, tid);
  __syncthreads();

  int lane = tid & 63, wave = tid >> 6;
  int lid = lane & 15, g = lane >> 4;
  int wb = wave * 64;

  f32x4 z4 = {0.f, 0.f, 0.f, 0.f};
  f32x4 acck[4][4], accq[4][4];
#pragma unroll
  for (int i = 0; i < 4; ++i)
#pragma unroll
    for (int j = 0; j < 4; ++j) { acck[i][j] = z4; accq[i][j] = z4; }
  f32x4 vacc = z4;

  for (int kk = 0; kk < 8; ++kk) {
    int kof = kk * 32 + g * 8;
    short8 ak[4], aq[4];
#pragma unroll
    for (int fm = 0; fm < 4; ++fm) {
      ak[fm] = *(const short8*)(wkx_bf + (size_t)(wb + fm * 16 + lid) * 256 + kof);
      aq[fm] = *(const short8*)(wqx_bf + (size_t)(wb + fm * 16 + lid) * 256 + kof);
    }
    short8 av = *(const short8*)(wvsum_bf + (size_t)lid * 256 + kof);
#pragma unroll
    for (int fn = 0; fn < 4; ++fn) {
      short8 bb = frag_b(xl, fn * 16 + lid, kk, g);
#pragma unroll
      for (int fm = 0; fm < 4; ++fm) {
        acck[fm][fn] = __builtin_amdgcn_mfma_f32_16x16x32_bf16(ak[fm], bb, acck[fm][fn], 0, 0, 0);
        accq[fm][fn] = __builtin_amdgcn_mfma_f32_16x16x32_bf16(aq[fm], bb, accq[fm][fn], 0, 0, 0);
      }
    }
    short8 bv = frag_b(xl, wave * 16 + lid, kk, g);
    vacc = __builtin_amdgcn_mfma_f32_16x16x32_bf16(av, bv, vacc, 0, 0, 0);
  }
  // vsum scatter: D row = head (0..7 valid -> g<2), col l = wave*16+lid
  if (g < 2) {
#pragma unroll
    for (int r = 0; r < 4; ++r)
      vsum_lds[(g * 4 + r) * 64 + wave * 16 + lid] = vacc[r];
  }
  __syncthreads();   // covers vsum write->read AND x-frag reads -> q-image writes

  // ---- k partials ----
  float wky_r[4][4];
#pragma unroll
  for (int fm = 0; fm < 4; ++fm)
#pragma unroll
    for (int r = 0; r < 4; ++r) wky_r[fm][r] = wky_lds[wb + fm * 16 + g * 4 + r];

  float s1[4][4], s2[4][4];
#pragma unroll
  for (int fm = 0; fm < 4; ++fm)
#pragma unroll
    for (int r = 0; r < 4; ++r) { s1[fm][r] = 0.f; s2[fm][r] = 0.f; }

#pragma unroll
  for (int fn = 0; fn < 4; ++fn) {
    int l = fn * 16 + lid;
    float yv = yup_lds[l];
#pragma unroll
    for (int fm = 0; fm < 4; ++fm) {
      float vs = vsum_lds[(wave * 2 + (fm >> 1)) * 64 + l];
#pragma unroll
      for (int r = 0; r < 4; ++r) {
        float v = acck[fm][fn][r] * (wky_r[fm][r] * yv);
        float kq = v > 0.f ? v + 1.f : __expf(v);   // elu(v)+1
        s1[fm][r] += kq;
        s2[fm][r] += kq * vs;
      }
    }
  }
#pragma unroll
  for (int fm = 0; fm < 4; ++fm)
#pragma unroll
    for (int r = 0; r < 4; ++r) {
      float a1 = s1[fm][r], a2 = s2[fm][r];
#pragma unroll
      for (int off = 1; off < 16; off <<= 1) {
        a1 += __shfl_xor(a1, off);
        a2 += __shfl_xor(a2, off);
      }
      if (lid == 0) {
        int c = wb + fm * 16 + g * 4 + r;
        part[(size_t)bid * 512 + c]       = a1;
        part[(size_t)bid * 512 + 256 + c] = a2;
      }
    }

  // ---- q -> image (reuse xbuf) ----
  float wqy_r[4][4];
#pragma unroll
  for (int fm = 0; fm < 4; ++fm)
#pragma unroll
    for (int r = 0; r < 4; ++r) wqy_r[fm][r] = wqy_lds[wb + fm * 16 + g * 4 + r];

#pragma unroll
  for (int fn = 0; fn < 4; ++fn) {
    int l = fn * 16 + lid;
    float yv = yup_lds[l];
#pragma unroll
    for (int fm = 0; fm < 4; ++fm) {
      ushort4v tw;
#pragma unroll
      for (int r = 0; r < 4; ++r) {
        float v = accq[fm][fn][r] * (wqy_r[fm][r] * yv);
        float qq = v > 0.f ? v + 1.f : __expf(v);   // elu(v)+1
        tw[r] = f2bf(qq);
      }
      int slot = (wave * 8 + fm * 2 + (g >> 1)) ^ swz(l);
      *(ushort4v*)(xl + (size_t)l * 512 + slot * 16 + (g & 1) * 8) = tw;
    }
  }
  __syncthreads();

  // ---- coalesced dump of the 32 KB image ----
  char* qdst = (char*)(qimg) + (size_t)bid * 32768;
#pragma unroll
  for (int i = 0; i < 8; ++i)
    *(u32x4*)(qdst + i * 4096 + tid * 16) = *(const u32x4*)(xl + i * 4096 + tid * 16);
}

// ---------------- mid: reduce partials, build ksum-rows + wout' --------------
__global__ __launch_bounds__(1024) void k_mid(
    const float* __restrict__ part, const float* __restrict__ w_out,
    u16* __restrict__ ksrows, u16* __restrict__ woutp) {
  __shared__ float red[2][512];
  __shared__ float ks_lds[256];
  __shared__ float kv_lds[256];
  int b = blockIdx.x, tid = threadIdx.x;
  int u = tid & 511, h = tid >> 9;
  float s = 0.f;
  for (int j = 0; j < 128; ++j)
    s += part[(size_t)(b * NT + h * 128 + j) * 512 + u];
  red[h][u] = s;
  __syncthreads();
  if (tid < 512) {
    float t = red[0][tid] + red[1][tid];
    if (tid < 256) ks_lds[tid] = t;
    else           kv_lds[tid - 256] = t;
  }
  __syncthreads();
  // ksrows[b]: [16][256] bf16; row 2h = bf16(ksum) masked to head h, row 2h+1 = residual
  u16* kr = ksrows + b * 4096;
  for (int j = tid; j < 4096; j += 1024) {
    int r = j >> 8, c = j & 255;
    int hh = c >> 5;
    float ks = ks_lds[c];
    u16 hi = f2bf(ks);
    u16 val = 0;
    if (r == 2 * hh) val = hi;
    else if (r == 2 * hh + 1) val = f2bf(ks - bf2f(hi));
    kr[j] = val;
  }
  // wout'[b][o][c] = bf16(w_out[o][c] * kvs[b][c])
  u16* wp = woutp + (size_t)b * 65536;
  for (int j = tid; j < 65536; j += 1024)
    wp[j] = f2bf(w_out[j] * kv_lds[j & 255]);
}

// ---------------- pass 2: z via MFMA, scale image, wout' GEMM ----------------
__global__ __launch_bounds__(256, 3) void k_pass2(
    const u16* __restrict__ qimg, const u16* __restrict__ woutp,
    const u16* __restrict__ ksrows, const float* __restrict__ b_out,
    float* __restrict__ out) {
  __shared__ u32x4 xbuf[2048];            // 32 KB
  __shared__ float zden_lds[8 * 64];
  __shared__ float bout_lds[256];
  char* xl = (char*)xbuf;

  int tid = threadIdx.x, bid = blockIdx.x;
  int b = bid >> 8, tile = bid & 255;
  int l0 = tile * LT;
  int lane = tid & 63, wave = tid >> 6;
  int lid = lane & 15, g = lane >> 4;

  bout_lds[tid] = b_out[tid];
  // async load of the pre-swizzled q image (linear copy)
  const char* gsrc = (const char*)qimg + (size_t)bid * 32768;
#pragma unroll
  for (int it = 0; it < 8; ++it) {
    int idx = it * 4 + wave;
    __builtin_amdgcn_global_load_lds(
        (const __attribute__((address_space(1))) void*)(gsrc + idx * 1024 + lane * 16),
        (__attribute__((address_space(3))) void*)(xl + idx * 1024),
        16, 0, 0);
  }
  __syncthreads();

  // ---- per-head z denominators: one MFMA row-block, A = masked ksum hi/lo ----
  f32x4 z4 = {0.f, 0.f, 0.f, 0.f};
  f32x4 zacc = z4;
  const u16* krb = ksrows + b * 4096;
  for (int kk = 0; kk < 8; ++kk) {
    int kof = kk * 32 + g * 8;
    short8 av = *(const short8*)(krb + lid * 256 + kof);
    short8 bv = frag_b(xl, wave * 16 + lid, kk, g);
    zacc = __builtin_amdgcn_mfma_f32_16x16x32_bf16(av, bv, zacc, 0, 0, 0);
  }
  // lane holds D rows g*4+r (r=0..3) = heads 2g (hi+lo), 2g+1 (hi+lo); col l = wave*16+lid
  {
    int l = wave * 16 + lid;
    zden_lds[(2 * g) * 64 + l]     = zacc[0] + zacc[1];
    zden_lds[(2 * g + 1) * 64 + l] = zacc[2] + zacc[3];
  }
  __syncthreads();

  // ---- scale image in LDS: q *= 1/(zden[head]+eps) ----
  {
    int l = tid & 63, grp = tid >> 6;
#pragma unroll
    for (int jo = 0; jo < 8; ++jo) {
      int o = grp * 8 + jo;
      int slot = o ^ swz(l);
      char* p = xl + (size_t)l * 512 + slot * 16;
      u32x4 v = *(u32x4*)p;
      float zz = 1.f / (zden_lds[(o >> 2) * 64 + l] + 1e-6f);
      u32x4 w;
#pragma unroll
      for (int q4 = 0; q4 < 4; ++q4) {
        u32 val = v[q4];
        float lo = bf2f((u16)(val & 0xffff)) * zz;
        float hi = bf2f((u16)(val >> 16)) * zz;
        w[q4] = pk2(lo, hi);
      }
      *(u32x4*)p = w;
    }
  }
  __syncthreads();

  // ---- main GEMM: out = wout'_b * (q ⊙ z) ----
  f32x4 acc[4][4];
#pragma unroll
  for (int i = 0; i < 4; ++i)
#pragma unroll
    for (int j = 0; j < 4; ++j) acc[i][j] = z4;
  int wb = wave * 64;
  const u16* wpb = woutp + (size_t)b * 65536;
  for (int kk = 0; kk < 8; ++kk) {
    int kof = kk * 32 + g * 8;
    short8 a[4];
#pragma unroll
    for (int fm = 0; fm < 4; ++fm)
      a[fm] = *(const short8*)(wpb + (size_t)(wb + fm * 16 + lid) * 256 + kof);
#pragma unroll
    for (int fn = 0; fn < 4; ++fn) {
      short8 bb = frag_b(xl, fn * 16 + lid, kk, g);
#pragma unroll
      for (int fm = 0; fm < 4; ++fm)
        acc[fm][fn] = __builtin_amdgcn_mfma_f32_16x16x32_bf16(a[fm], bb, acc[fm][fn], 0, 0, 0);
    }
  }

  // ---- epilogue ----
#pragma unroll
  for (int fm = 0; fm < 4; ++fm) {
#pragma unroll
    for (int r = 0; r < 4; ++r) {
      int o = wb + fm * 16 + g * 4 + r;
      float bo = bout_lds[o];
      size_t base = ((size_t)b * 256 + o) * LDIM + l0;
#pragma unroll
      for (int fn = 0; fn < 4; ++fn)
        out[base + fn * 16 + lid] = acc[fm][fn][r] + bo;
    }
  }
}

// ---------------- launch -------------------------------------------------------
extern "C" void kernel_launch(void* const* d_in, const int* in_sizes, int n_in,
                              void* d_out, int out_size, void* d_ws, size_t ws_size,
                              hipStream_t stream) {
  const float* x     = (const float*)d_in[0];
  const float* y     = (const float*)d_in[1];
  const float* wq_x  = (const float*)d_in[2];
  const float* wk_x  = (const float*)d_in[3];
  const float* wv    = (const float*)d_in[4];
  const float* wq_y  = (const float*)d_in[5];
  const float* wk_y  = (const float*)d_in[6];
  const float* w_out = (const float*)d_in[7];
  const float* b_out = (const float*)d_in[8];
  float* out = (float*)d_out;

  char* ws = (char*)d_ws;
  u16*   qimg     = (u16*)(ws + 0);            // 8*256 tiles * 32 KB = 64 MB
  float* part     = (float*)(ws + 67108864);   // 2048*512*4 = 4 MB
  float* yup      = (float*)(ws + 71303168);   // 512 KB
  u16*   wqx_bf   = (u16*)(ws + 71827456);     // 128 KB
  u16*   wkx_bf   = (u16*)(ws + 71958528);     // 128 KB
  u16*   wvsum_bf = (u16*)(ws + 72089600);     // 8 KB
  u16*   ksrows   = (u16*)(ws + 72097792);     // 8*16*256*2 = 64 KB
  u16*   woutp    = (u16*)(ws + 72163328);     // 8*256*256*2 = 1 MB

  k_prep<<<512, 256, 0, stream>>>(wq_x, wk_x, wv, y, wqx_bf, wkx_bf, wvsum_bf, yup);
  k_pass1<<<NB * NT, 256, 0, stream>>>(x, wkx_bf, wqx_bf, wvsum_bf, wk_y, wq_y,
                                       yup, qimg, part);
  k_mid<<<NB, 1024, 0, stream>>>(part, w_out, ksrows, woutp);
  k_pass2<<<NB * NT, 256, 0, stream>>>(qimg, woutp, ksrows, b_out, out);
}

// Round 7
// 184.531 us; speedup vs baseline: 1.0416x; 1.0416x over previous
//
#include <hip/hip_runtime.h>
#include <hip/hip_bf16.h>

typedef unsigned short u16;
typedef unsigned int   u32;
using short8   = __attribute__((ext_vector_type(8))) short;
using f32x4    = __attribute__((ext_vector_type(4))) float;
using ushort4v = __attribute__((ext_vector_type(4))) unsigned short;
using u32x4    = __attribute__((ext_vector_type(4))) unsigned int;

#define LDIM 16384
#define LT   128
#define NT   128   // L tiles per batch
#define NB   8

__device__ __forceinline__ u16 f2bf(float f) {
  u32 u = __float_as_uint(f);
  u = (u + 0x7FFFu + ((u >> 16) & 1u)) >> 16;   // RTNE
  return (u16)u;
}

__device__ __forceinline__ u32 pk2(float a, float b) {
  __hip_bfloat162 h = __float22bfloat162_rn(make_float2(a, b));  // a -> low
  return *(u32*)&h;
}

// image layout: byte(l,c) = l*512 + slot*16 + (c&7)*2,
//   slot = (c>>3) ^ swz(l),  swz(l) = ((l>>2)&31) ^ ((l&3)<<2)
__device__ __forceinline__ int swz(int l) {
  return ((l >> 2) & 31) ^ ((l & 3) << 2);
}
// B-fragment read: rows ll, k-slice = kk*32 + g*8 .. +7  (c-octet = kk*4+g)
__device__ __forceinline__ short8 frag_b(const char* xl, int ll, int kk, int g) {
  int slot = (kk * 4 + g) ^ swz(ll);
  return *(const short8*)(xl + (size_t)ll * 512 + slot * 16);
}

// ---------------- prep: weight bf16 conversion, wvsum, bilinear upsample ----
__global__ void k_prep(const float* __restrict__ wq_x, const float* __restrict__ wk_x,
                       const float* __restrict__ w_out, const float* __restrict__ wv,
                       const float* __restrict__ y,
                       u16* __restrict__ wqx_bf, u16* __restrict__ wkx_bf,
                       u16* __restrict__ wout_bf, u16* __restrict__ wvsum_bf,
                       float* __restrict__ yup) {
  int id = blockIdx.x * 256 + threadIdx.x;
  if (id < 65536) {
    wqx_bf[id]  = f2bf(wq_x[id]);
    wkx_bf[id]  = f2bf(wk_x[id]);
    wout_bf[id] = f2bf(w_out[id]);
  }
  if (id < 4096) {  // wvsum padded to 16 rows (rows 8..15 zero)
    int r = id >> 8, c = id & 255;
    float s = 0.f;
    if (r < 8) {
      for (int d2 = 0; d2 < 32; ++d2) s += wv[(r * 32 + d2) * 256 + c];
    }
    wvsum_bf[id] = f2bf(s);
  }
  if (id < 131072) {  // bilinear 2x upsample, half-pixel (align_corners=False)
    int b = id >> 14, rem = id & 16383, i = rem >> 7, j = rem & 127;
    float si = 0.5f * i - 0.25f, sj = 0.5f * j - 0.25f;
    int i0 = (int)floorf(si), j0 = (int)floorf(sj);
    float fi = si - (float)i0, fj = sj - (float)j0;
    int i0c = i0 < 0 ? 0 : i0, i1c = i0 + 1 > 63 ? 63 : i0 + 1;
    int j0c = j0 < 0 ? 0 : j0, j1c = j0 + 1 > 63 ? 63 : j0 + 1;
    const float* yb = y + b * 4096;
    float v = (1.f - fi) * ((1.f - fj) * yb[i0c * 64 + j0c] + fj * yb[i0c * 64 + j1c])
            +        fi  * ((1.f - fj) * yb[i1c * 64 + j0c] + fj * yb[i1c * 64 + j1c]);
    yup[id] = v;
  }
}

// ---------------- convert: x f32 -> bf16 transposed+swizzled image -----------
// Register transpose of 8c x 4l blocks; wave-coalesced 16B stores. No LDS.
__device__ __forceinline__ void conv_one_octet(char* dst, const float* p, int so, int k) {
  float4 r0 = *(const float4*)(p + 0 * LDIM);
  float4 r1 = *(const float4*)(p + 1 * LDIM);
  float4 r2 = *(const float4*)(p + 2 * LDIM);
  float4 r3 = *(const float4*)(p + 3 * LDIM);
  float4 r4 = *(const float4*)(p + 4 * LDIM);
  float4 r5 = *(const float4*)(p + 5 * LDIM);
  float4 r6 = *(const float4*)(p + 6 * LDIM);
  float4 r7 = *(const float4*)(p + 7 * LDIM);
  const float* f0 = (const float*)&r0; const float* f1 = (const float*)&r1;
  const float* f2 = (const float*)&r2; const float* f3 = (const float*)&r3;
  const float* f4 = (const float*)&r4; const float* f5 = (const float*)&r5;
  const float* f6 = (const float*)&r6; const float* f7 = (const float*)&r7;
#pragma unroll
  for (int e = 0; e < 4; ++e) {
    int l = k * 4 + e;
    u32x4 wv;
    wv.x = pk2(f0[e], f1[e]);
    wv.y = pk2(f2[e], f3[e]);
    wv.z = pk2(f4[e], f5[e]);
    wv.w = pk2(f6[e], f7[e]);
    int slot = so ^ swz(l);
    *(u32x4*)(dst + (size_t)l * 512 + slot * 16) = wv;
  }
}

__global__ __launch_bounds__(256) void k_conv(const float* __restrict__ x,
                                              u16* __restrict__ xbf) {
  int tid = threadIdx.x, bid = blockIdx.x;   // grid 1024 = 8 b x 128 tiles
  int b = bid >> 7, tile = bid & 127;
  int l0 = tile * LT;
  int k = tid & 31, co = tid >> 5;           // l-quad, base c-octet (0..7)
  char* dst = (char*)xbf + (size_t)bid * 65536;
  const float* bp = x + ((size_t)b * 256 + co * 8) * LDIM + l0 + k * 4;
#pragma unroll 1
  for (int oi = 0; oi < 4; ++oi)
    conv_one_octet(dst, bp + (size_t)(oi * 64) * LDIM, co + oi * 8, k);
}

// ---------------- tile load: image -> LDS (linear, zero VALU) ----------------
__device__ __forceinline__ void gload_tile(char* xl, const char* gsrc, int tid) {
  int lane = tid & 63, wave = tid >> 6;
#pragma unroll
  for (int it = 0; it < 16; ++it) {
    int idx = it * 4 + wave;
    __builtin_amdgcn_global_load_lds(
        (const __attribute__((address_space(1))) void*)(gsrc + idx * 1024 + lane * 16),
        (__attribute__((address_space(3))) void*)(xl + idx * 1024),
        16, 0, 0);
  }
}

// ---------------- pass 1: ksum / kvs partials ---------------------------------
__global__ __launch_bounds__(256, 2) void k_pass1(
    const u16* __restrict__ xbf, const u16* __restrict__ wkx_bf,
    const u16* __restrict__ wvsum_bf, const float* __restrict__ wk_y,
    const float* __restrict__ yup, float* __restrict__ part) {
  __shared__ u32x4 xbuf[4096];            // 64 KB
  __shared__ float vsum_lds[8 * 128];     // [head][l]
  __shared__ float yup_lds[128];
  __shared__ float wky_lds[256];
  char* xl = (char*)xbuf;

  int tid = threadIdx.x, bid = blockIdx.x;
  int b = bid >> 7, tile = bid & 127;
  int l0 = tile * LT;

  if (tid < 128) yup_lds[tid] = yup[b * LDIM + l0 + tid];
  wky_lds[tid] = wk_y[tid];
  gload_tile(xl, (const char*)xbf + (size_t)bid * 65536, tid);
  __syncthreads();

  int lane = tid & 63, wave = tid >> 6;
  int lid = lane & 15, g = lane >> 4;
  int wb = wave * 64;

  f32x4 z4 = {0.f, 0.f, 0.f, 0.f};
  f32x4 acc[4][8];
#pragma unroll
  for (int i = 0; i < 4; ++i)
#pragma unroll
    for (int j = 0; j < 8; ++j) acc[i][j] = z4;
  f32x4 vacc[2] = {z4, z4};

  for (int kk = 0; kk < 8; ++kk) {
    int kof = kk * 32 + g * 8;
    short8 a[4];
#pragma unroll
    for (int fm = 0; fm < 4; ++fm)
      a[fm] = *(const short8*)(wkx_bf + (size_t)(wb + fm * 16 + lid) * 256 + kof);
    short8 av = *(const short8*)(wvsum_bf + (size_t)lid * 256 + kof);
#pragma unroll
    for (int fn = 0; fn < 8; ++fn) {
      short8 bb = frag_b(xl, fn * 16 + lid, kk, g);
#pragma unroll
      for (int fm = 0; fm < 4; ++fm)
        acc[fm][fn] = __builtin_amdgcn_mfma_f32_16x16x32_bf16(a[fm], bb, acc[fm][fn], 0, 0, 0);
    }
    // vsum mini-GEMM: this wave covers fn = 2*wave, 2*wave+1
#pragma unroll
    for (int fv = 0; fv < 2; ++fv) {
      short8 bb = frag_b(xl, (wave * 2 + fv) * 16 + lid, kk, g);
      vacc[fv] = __builtin_amdgcn_mfma_f32_16x16x32_bf16(av, bb, vacc[fv], 0, 0, 0);
    }
  }
  // scatter vsum rows 0..7 (g<2 holds rows g*4+r), col l = (wave*2+fv)*16+lid
  if (g < 2) {
#pragma unroll
    for (int fv = 0; fv < 2; ++fv)
#pragma unroll
      for (int r = 0; r < 4; ++r)
        vsum_lds[(g * 4 + r) * 128 + (wave * 2 + fv) * 16 + lid] = vacc[fv][r];
  }
  __syncthreads();

  float wky_r[4][4];
#pragma unroll
  for (int fm = 0; fm < 4; ++fm)
#pragma unroll
    for (int r = 0; r < 4; ++r) wky_r[fm][r] = wky_lds[wb + fm * 16 + g * 4 + r];

  float s1[4][4], s2[4][4];
#pragma unroll
  for (int fm = 0; fm < 4; ++fm)
#pragma unroll
    for (int r = 0; r < 4; ++r) { s1[fm][r] = 0.f; s2[fm][r] = 0.f; }

#pragma unroll
  for (int fn = 0; fn < 8; ++fn) {
    int l = fn * 16 + lid;
    float yv = yup_lds[l];
#pragma unroll
    for (int fm = 0; fm < 4; ++fm) {
      float vs = vsum_lds[(wave * 2 + (fm >> 1)) * 128 + l];   // head of c-rows
#pragma unroll
      for (int r = 0; r < 4; ++r) {
        float v = acc[fm][fn][r] * (wky_r[fm][r] * yv);
        float kq = v > 0.f ? v + 1.f : __expf(v);   // elu(v)+1
        s1[fm][r] += kq;
        s2[fm][r] += kq * vs;
      }
    }
  }
#pragma unroll
  for (int fm = 0; fm < 4; ++fm)
#pragma unroll
    for (int r = 0; r < 4; ++r) {
      float a1 = s1[fm][r], a2 = s2[fm][r];
#pragma unroll
      for (int off = 1; off < 16; off <<= 1) {
        a1 += __shfl_xor(a1, off);
        a2 += __shfl_xor(a2, off);
      }
      if (lid == 0) {
        int c = wb + fm * 16 + g * 4 + r;
        part[(size_t)bid * 512 + c]       = a1;
        part[(size_t)bid * 512 + 256 + c] = a2;
      }
    }
}

// ---------------- reduce partials -> ksum, kvs --------------------------------
__global__ __launch_bounds__(1024) void k_reduce(
    const float* __restrict__ part, float* __restrict__ ksum, float* __restrict__ kvs) {
  __shared__ float red[2][512];
  int b = blockIdx.x, tid = threadIdx.x;
  int u = tid & 511, h = tid >> 9;
  float s = 0.f;
  for (int j = 0; j < 64; ++j)
    s += part[(size_t)(b * NT + h * 64 + j) * 512 + u];
  red[h][u] = s;
  __syncthreads();
  if (tid < 512) {
    float t = red[0][tid] + red[1][tid];
    if (tid < 256) ksum[b * 256 + tid] = t;
    else           kvs[b * 256 + tid - 256] = t;
  }
}

// ---------------- pass 2: q, z, t, w_out GEMM, output -------------------------
__global__ __launch_bounds__(256, 2) void k_pass2(
    const u16* __restrict__ xbf, const u16* __restrict__ wqx_bf,
    const u16* __restrict__ wout_bf, const float* __restrict__ wq_y,
    const float* __restrict__ yup, const float* __restrict__ ksum,
    const float* __restrict__ kvs, const float* __restrict__ b_out,
    float* __restrict__ out) {
  __shared__ u32x4 xbuf[4096];            // 64 KB
  __shared__ float yup_lds[128];
  __shared__ float wqy_lds[256];
  __shared__ float ksum_lds[256];
  __shared__ float kvs_lds[256];
  __shared__ float bout_lds[256];
  char* xl = (char*)xbuf;

  int tid = threadIdx.x, bid = blockIdx.x;
  int b = bid >> 7, tile = bid & 127;
  int l0 = tile * LT;

  if (tid < 128) yup_lds[tid] = yup[b * LDIM + l0 + tid];
  wqy_lds[tid]  = wq_y[tid];
  ksum_lds[tid] = ksum[b * 256 + tid];
  kvs_lds[tid]  = kvs[b * 256 + tid];
  bout_lds[tid] = b_out[tid];
  gload_tile(xl, (const char*)xbf + (size_t)bid * 65536, tid);
  __syncthreads();

  int lane = tid & 63, wave = tid >> 6;
  int lid = lane & 15, g = lane >> 4;
  int wb = wave * 64;

  f32x4 z4 = {0.f, 0.f, 0.f, 0.f};
  f32x4 acc[4][8];
#pragma unroll
  for (int i = 0; i < 4; ++i)
#pragma unroll
    for (int j = 0; j < 8; ++j) acc[i][j] = z4;

  // GEMM1: q_x = wq_x * x
  for (int kk = 0; kk < 8; ++kk) {
    int kof = kk * 32 + g * 8;
    short8 a[4];
#pragma unroll
    for (int fm = 0; fm < 4; ++fm)
      a[fm] = *(const short8*)(wqx_bf + (size_t)(wb + fm * 16 + lid) * 256 + kof);
#pragma unroll
    for (int fn = 0; fn < 8; ++fn) {
      short8 bb = frag_b(xl, fn * 16 + lid, kk, g);
#pragma unroll
      for (int fm = 0; fm < 4; ++fm)
        acc[fm][fn] = __builtin_amdgcn_mfma_f32_16x16x32_bf16(a[fm], bb, acc[fm][fn], 0, 0, 0);
    }
  }
  __syncthreads();  // x_lds reads done; buffer reused for t

  float wqy_r[4][4], ks_r[4][4], kv_r[4][4];
#pragma unroll
  for (int fm = 0; fm < 4; ++fm)
#pragma unroll
    for (int r = 0; r < 4; ++r) {
      int c = wb + fm * 16 + g * 4 + r;
      wqy_r[fm][r] = wqy_lds[c];
      ks_r[fm][r]  = ksum_lds[c];
      kv_r[fm][r]  = kvs_lds[c];
    }

#pragma unroll
  for (int fn = 0; fn < 8; ++fn) {
    int l = fn * 16 + lid;
    float yv = yup_lds[l];
    float q[4][4];
    float d0 = 0.f, d1 = 0.f;
#pragma unroll
    for (int fm = 0; fm < 4; ++fm)
#pragma unroll
      for (int r = 0; r < 4; ++r) {
        float v = acc[fm][fn][r] * (wqy_r[fm][r] * yv);
        float qq = v > 0.f ? v + 1.f : __expf(v);   // elu(v)+1
        q[fm][r] = qq;
        if (fm < 2) d0 += qq * ks_r[fm][r]; else d1 += qq * ks_r[fm][r];
      }
    // lanes {lid,lid+16,lid+32,lid+48} share the same l -> head-sum over 32 c
    d0 += __shfl_xor(d0, 16); d0 += __shfl_xor(d0, 32);
    d1 += __shfl_xor(d1, 16); d1 += __shfl_xor(d1, 32);
    float zz0 = 1.f / (d0 + 1e-6f), zz1 = 1.f / (d1 + 1e-6f);
#pragma unroll
    for (int fm = 0; fm < 4; ++fm) {
      float zz = fm < 2 ? zz0 : zz1;
      ushort4v tw;
#pragma unroll
      for (int r = 0; r < 4; ++r) tw[r] = f2bf(q[fm][r] * kv_r[fm][r] * zz);
      int slot = (wave * 8 + fm * 2 + (g >> 1)) ^ swz(l);
      *(ushort4v*)(xl + (size_t)l * 512 + slot * 16 + (g & 1) * 8) = tw;
    }
  }
  __syncthreads();

  // GEMM2: out = w_out * t
#pragma unroll
  for (int i = 0; i < 4; ++i)
#pragma unroll
    for (int j = 0; j < 8; ++j) acc[i][j] = z4;
  for (int kk = 0; kk < 8; ++kk) {
    int kof = kk * 32 + g * 8;
    short8 a[4];
#pragma unroll
    for (int fm = 0; fm < 4; ++fm)
      a[fm] = *(const short8*)(wout_bf + (size_t)(wb + fm * 16 + lid) * 256 + kof);
#pragma unroll
    for (int fn = 0; fn < 8; ++fn) {
      short8 bb = frag_b(xl, fn * 16 + lid, kk, g);
#pragma unroll
      for (int fm = 0; fm < 4; ++fm)
        acc[fm][fn] = __builtin_amdgcn_mfma_f32_16x16x32_bf16(a[fm], bb, acc[fm][fn], 0, 0, 0);
    }
  }

  // epilogue
#pragma unroll
  for (int fm = 0; fm < 4; ++fm) {
#pragma unroll
    for (int r = 0; r < 4; ++r) {
      int o = wb + fm * 16 + g * 4 + r;
      float bo = bout_lds[o];
      size_t base = ((size_t)b * 256 + o) * LDIM + l0;
#pragma unroll
      for (int fn = 0; fn < 8; ++fn)
        out[base + fn * 16 + lid] = acc[fm][fn][r] + bo;
    }
  }
}

// ---------------- launch -------------------------------------------------------
extern "C" void kernel_launch(void* const* d_in, const int* in_sizes, int n_in,
                              void* d_out, int out_size, void* d_ws, size_t ws_size,
                              hipStream_t stream) {
  const float* x     = (const float*)d_in[0];
  const float* y     = (const float*)d_in[1];
  const float* wq_x  = (const float*)d_in[2];
  const float* wk_x  = (const float*)d_in[3];
  const float* wv    = (const float*)d_in[4];
  const float* wq_y  = (const float*)d_in[5];
  const float* wk_y  = (const float*)d_in[6];
  const float* w_out = (const float*)d_in[7];
  const float* b_out = (const float*)d_in[8];
  float* out = (float*)d_out;

  char* ws = (char*)d_ws;
  float* yup      = (float*)(ws + 0);         // 512 KB
  u16*   wqx_bf   = (u16*)(ws + 524288);      // 128 KB
  u16*   wkx_bf   = (u16*)(ws + 655360);      // 128 KB
  u16*   wout_bf  = (u16*)(ws + 786432);      // 128 KB
  u16*   wvsum_bf = (u16*)(ws + 917504);      // 8 KB
  float* ksum     = (float*)(ws + 925696);    // 8 KB
  float* kvs      = (float*)(ws + 933888);    // 8 KB
  float* part     = (float*)(ws + 942080);    // 2 MB
  u16*   xbf      = (u16*)(ws + 4194304);     // 64 MB bf16 x image (proven fits: R2)

  k_prep<<<512, 256, 0, stream>>>(wq_x, wk_x, w_out, wv, y,
                                  wqx_bf, wkx_bf, wout_bf, wvsum_bf, yup);
  k_conv<<<NB * NT, 256, 0, stream>>>(x, xbf);
  k_pass1<<<NB * NT, 256, 0, stream>>>(xbf, wkx_bf, wvsum_bf, wk_y, yup, part);
  k_reduce<<<NB, 1024, 0, stream>>>(part, ksum, kvs);
  k_pass2<<<NB * NT, 256, 0, stream>>>(xbf, wqx_bf, wout_bf, wq_y, yup,
                                       ksum, kvs, b_out, out);
}

// Round 8
// 150.376 us; speedup vs baseline: 1.2781x; 1.2271x over previous
//
#include <hip/hip_runtime.h>
#include <hip/hip_bf16.h>

typedef unsigned short u16;
typedef unsigned int   u32;
using short8   = __attribute__((ext_vector_type(8))) short;
using f32x4    = __attribute__((ext_vector_type(4))) float;
using ushort4v = __attribute__((ext_vector_type(4))) unsigned short;
using u32x4    = __attribute__((ext_vector_type(4))) unsigned int;

#define LDIM 16384
#define LT1  128
#define NT1  128   // pass1 L tiles per batch
#define LT2  64
#define NT2  256   // pass2 L tiles per batch
#define NB   8

__device__ __forceinline__ u16 f2bf(float f) {
  u32 u = __float_as_uint(f);
  u = (u + 0x7FFFu + ((u >> 16) & 1u)) >> 16;   // RTNE
  return (u16)u;
}

__device__ __forceinline__ u32 pk2(float a, float b) {
  __hip_bfloat162 h = __float22bfloat162_rn(make_float2(a, b));  // a -> low
  return *(u32*)&h;
}

// image layout: byte(l,c) = l*512 + slot*16 + (c&7)*2,
//   slot = (c>>3) ^ swz(l),  swz(l) = ((l>>2)&31) ^ ((l&3)<<2)
__device__ __forceinline__ int swz(int l) {
  return ((l >> 2) & 31) ^ ((l & 3) << 2);
}
// B-fragment read: row ll, k-slice = kk*32 + g*8 .. +7  (c-octet = kk*4+g)
__device__ __forceinline__ short8 frag_b(const char* xl, int ll, int kk, int g) {
  int slot = (kk * 4 + g) ^ swz(ll);
  return *(const short8*)(xl + (size_t)ll * 512 + slot * 16);
}

// ---------------- prep: weight bf16 conversion, wvsum, bilinear upsample ----
__global__ void k_prep(const float* __restrict__ wq_x, const float* __restrict__ wk_x,
                       const float* __restrict__ w_out, const float* __restrict__ wv,
                       const float* __restrict__ y,
                       u16* __restrict__ wqx_bf, u16* __restrict__ wkx_bf,
                       u16* __restrict__ wout_bf, u16* __restrict__ wvsum_bf,
                       float* __restrict__ yup) {
  int id = blockIdx.x * 256 + threadIdx.x;
  if (id < 65536) {
    wqx_bf[id]  = f2bf(wq_x[id]);
    wkx_bf[id]  = f2bf(wk_x[id]);
    wout_bf[id] = f2bf(w_out[id]);
  }
  if (id < 4096) {  // wvsum padded to 16 rows (rows 8..15 zero)
    int r = id >> 8, c = id & 255;
    float s = 0.f;
    if (r < 8) {
      for (int d2 = 0; d2 < 32; ++d2) s += wv[(r * 32 + d2) * 256 + c];
    }
    wvsum_bf[id] = f2bf(s);
  }
  if (id < 131072) {  // bilinear 2x upsample, half-pixel (align_corners=False)
    int b = id >> 14, rem = id & 16383, i = rem >> 7, j = rem & 127;
    float si = 0.5f * i - 0.25f, sj = 0.5f * j - 0.25f;
    int i0 = (int)floorf(si), j0 = (int)floorf(sj);
    float fi = si - (float)i0, fj = sj - (float)j0;
    int i0c = i0 < 0 ? 0 : i0, i1c = i0 + 1 > 63 ? 63 : i0 + 1;
    int j0c = j0 < 0 ? 0 : j0, j1c = j0 + 1 > 63 ? 63 : j0 + 1;
    const float* yb = y + b * 4096;
    float v = (1.f - fi) * ((1.f - fj) * yb[i0c * 64 + j0c] + fj * yb[i0c * 64 + j1c])
            +        fi  * ((1.f - fj) * yb[i1c * 64 + j0c] + fj * yb[i1c * 64 + j1c]);
    yup[id] = v;
  }
}

// ---------------- staging: x f32 -> swizzled LDS bf16 image ------------------
__device__ __forceinline__ void stage_one_octet(char* xl, const float* p, int so, int k) {
  float4 r0 = *(const float4*)(p + 0 * LDIM);
  float4 r1 = *(const float4*)(p + 1 * LDIM);
  float4 r2 = *(const float4*)(p + 2 * LDIM);
  float4 r3 = *(const float4*)(p + 3 * LDIM);
  float4 r4 = *(const float4*)(p + 4 * LDIM);
  float4 r5 = *(const float4*)(p + 5 * LDIM);
  float4 r6 = *(const float4*)(p + 6 * LDIM);
  float4 r7 = *(const float4*)(p + 7 * LDIM);
  const float* f0 = (const float*)&r0; const float* f1 = (const float*)&r1;
  const float* f2 = (const float*)&r2; const float* f3 = (const float*)&r3;
  const float* f4 = (const float*)&r4; const float* f5 = (const float*)&r5;
  const float* f6 = (const float*)&r6; const float* f7 = (const float*)&r7;
#pragma unroll
  for (int e = 0; e < 4; ++e) {
    int l = k * 4 + e;
    u32x4 wv;
    wv.x = pk2(f0[e], f1[e]);
    wv.y = pk2(f2[e], f3[e]);
    wv.z = pk2(f4[e], f5[e]);
    wv.w = pk2(f6[e], f7[e]);
    int slot = so ^ swz(l);
    *(u32x4*)(xl + (size_t)l * 512 + slot * 16) = wv;
  }
}

// pass1 staging: LT=128, lane k=tid&31 spans l; full unroll (proven envelope)
__device__ __forceinline__ void stage_x128(char* xl, const float* __restrict__ x,
                                           int b, int l0, int tid) {
  int k = tid & 31, co = tid >> 5;
  const float* bp = x + ((size_t)b * 256 + co * 8) * LDIM + l0 + k * 4;
#pragma unroll
  for (int oi = 0; oi < 4; ++oi)
    stage_one_octet(xl, bp + (size_t)(oi * 64) * LDIM, co + oi * 8, k);
}

// pass2 staging: LT=64, low-reg (one octet in flight)
__device__ __forceinline__ void stage_x64(char* xl, const float* __restrict__ x,
                                          int b, int l0, int tid) {
  int k = tid & 15, cog = tid >> 4;
  const float* bp = x + ((size_t)b * 256 + cog * 8) * LDIM + l0 + k * 4;
#pragma unroll 1
  for (int oi = 0; oi < 2; ++oi)
    stage_one_octet(xl, bp + (size_t)(oi * 128) * LDIM, cog + oi * 16, k);
}

// ---------------- pass 1: ksum / kvs partials (R5 verbatim) -------------------
__global__ __launch_bounds__(256, 2) void k_pass1(
    const float* __restrict__ x, const u16* __restrict__ wkx_bf,
    const u16* __restrict__ wvsum_bf, const float* __restrict__ wk_y,
    const float* __restrict__ yup, float* __restrict__ part) {
  __shared__ u32x4 xbuf[4096];            // 64 KB
  __shared__ float vsum_lds[8 * 128];     // [head][l]
  __shared__ float yup_lds[128];
  __shared__ float wky_lds[256];
  char* xl = (char*)xbuf;

  int tid = threadIdx.x, bid = blockIdx.x;
  int b = bid >> 7, tile = bid & 127;
  int l0 = tile * LT1;

  if (tid < 128) yup_lds[tid] = yup[b * LDIM + l0 + tid];
  wky_lds[tid] = wk_y[tid];
  stage_x128(xl, x, b, l0, tid);
  __syncthreads();

  int lane = tid & 63, wave = tid >> 6;
  int lid = lane & 15, g = lane >> 4;
  int wb = wave * 64;

  f32x4 z4 = {0.f, 0.f, 0.f, 0.f};
  f32x4 acc[4][8];
#pragma unroll
  for (int i = 0; i < 4; ++i)
#pragma unroll
    for (int j = 0; j < 8; ++j) acc[i][j] = z4;
  f32x4 vacc[2] = {z4, z4};

  for (int kk = 0; kk < 8; ++kk) {
    int kof = kk * 32 + g * 8;
    short8 a[4];
#pragma unroll
    for (int fm = 0; fm < 4; ++fm)
      a[fm] = *(const short8*)(wkx_bf + (size_t)(wb + fm * 16 + lid) * 256 + kof);
    short8 av = *(const short8*)(wvsum_bf + (size_t)lid * 256 + kof);
#pragma unroll
    for (int fn = 0; fn < 8; ++fn) {
      short8 bb = frag_b(xl, fn * 16 + lid, kk, g);
#pragma unroll
      for (int fm = 0; fm < 4; ++fm)
        acc[fm][fn] = __builtin_amdgcn_mfma_f32_16x16x32_bf16(a[fm], bb, acc[fm][fn], 0, 0, 0);
    }
#pragma unroll
    for (int fv = 0; fv < 2; ++fv) {
      short8 bb = frag_b(xl, (wave * 2 + fv) * 16 + lid, kk, g);
      vacc[fv] = __builtin_amdgcn_mfma_f32_16x16x32_bf16(av, bb, vacc[fv], 0, 0, 0);
    }
  }
  if (g < 2) {
#pragma unroll
    for (int fv = 0; fv < 2; ++fv)
#pragma unroll
      for (int r = 0; r < 4; ++r)
        vsum_lds[(g * 4 + r) * 128 + (wave * 2 + fv) * 16 + lid] = vacc[fv][r];
  }
  __syncthreads();

  float wky_r[4][4];
#pragma unroll
  for (int fm = 0; fm < 4; ++fm)
#pragma unroll
    for (int r = 0; r < 4; ++r) wky_r[fm][r] = wky_lds[wb + fm * 16 + g * 4 + r];

  float s1[4][4], s2[4][4];
#pragma unroll
  for (int fm = 0; fm < 4; ++fm)
#pragma unroll
    for (int r = 0; r < 4; ++r) { s1[fm][r] = 0.f; s2[fm][r] = 0.f; }

#pragma unroll
  for (int fn = 0; fn < 8; ++fn) {
    int l = fn * 16 + lid;
    float yv = yup_lds[l];
#pragma unroll
    for (int fm = 0; fm < 4; ++fm) {
      float vs = vsum_lds[(wave * 2 + (fm >> 1)) * 128 + l];
#pragma unroll
      for (int r = 0; r < 4; ++r) {
        float v = acc[fm][fn][r] * (wky_r[fm][r] * yv);
        float kq = v > 0.f ? v + 1.f : __expf(v);   // elu(v)+1
        s1[fm][r] += kq;
        s2[fm][r] += kq * vs;
      }
    }
  }
#pragma unroll
  for (int fm = 0; fm < 4; ++fm)
#pragma unroll
    for (int r = 0; r < 4; ++r) {
      float a1 = s1[fm][r], a2 = s2[fm][r];
#pragma unroll
      for (int off = 1; off < 16; off <<= 1) {
        a1 += __shfl_xor(a1, off);
        a2 += __shfl_xor(a2, off);
      }
      if (lid == 0) {
        int c = wb + fm * 16 + g * 4 + r;
        part[(size_t)bid * 512 + c]       = a1;
        part[(size_t)bid * 512 + 256 + c] = a2;
      }
    }
}

// ---------------- reduce partials -> ksum, kvs --------------------------------
__global__ __launch_bounds__(1024) void k_reduce(
    const float* __restrict__ part, float* __restrict__ ksum, float* __restrict__ kvs) {
  __shared__ float red[2][512];
  int b = blockIdx.x, tid = threadIdx.x;
  int u = tid & 511, h = tid >> 9;
  float s = 0.f;
  for (int j = 0; j < 64; ++j)
    s += part[(size_t)(b * NT1 + h * 64 + j) * 512 + u];
  red[h][u] = s;
  __syncthreads();
  if (tid < 512) {
    float t = red[0][tid] + red[1][tid];
    if (tid < 256) ksum[b * 256 + tid] = t;
    else           kvs[b * 256 + tid - 256] = t;
  }
}

// ---------------- pass 2: LT=64, small footprint, 3 waves/SIMD ---------------
__global__ __launch_bounds__(256, 3) void k_pass2(
    const float* __restrict__ x, const u16* __restrict__ wqx_bf,
    const u16* __restrict__ wout_bf, const float* __restrict__ wq_y,
    const float* __restrict__ yup, const float* __restrict__ ksum,
    const float* __restrict__ kvs, const float* __restrict__ b_out,
    float* __restrict__ out) {
  __shared__ u32x4 xbuf[2048];            // 32 KB
  __shared__ __align__(16) float yup_lds[64];
  __shared__ __align__(16) float wqy_lds[256];
  __shared__ __align__(16) float ksum_lds[256];
  __shared__ __align__(16) float kvs_lds[256];
  __shared__ __align__(16) float bout_lds[256];
  char* xl = (char*)xbuf;

  int tid = threadIdx.x, bid = blockIdx.x;
  int b = bid >> 8, tile = bid & 255;
  int l0 = tile * LT2;

  if (tid < 64) yup_lds[tid] = yup[b * LDIM + l0 + tid];
  wqy_lds[tid]  = wq_y[tid];
  ksum_lds[tid] = ksum[b * 256 + tid];
  kvs_lds[tid]  = kvs[b * 256 + tid];
  bout_lds[tid] = b_out[tid];
  stage_x64(xl, x, b, l0, tid);
  __syncthreads();

  int lane = tid & 63, wave = tid >> 6;
  int lid = lane & 15, g = lane >> 4;
  int wb = wave * 64;

  f32x4 z4 = {0.f, 0.f, 0.f, 0.f};
  f32x4 acc[4][4];
#pragma unroll
  for (int i = 0; i < 4; ++i)
#pragma unroll
    for (int j = 0; j < 4; ++j) acc[i][j] = z4;

  // GEMM1: q_x = wq_x * x
  for (int kk = 0; kk < 8; ++kk) {
    int kof = kk * 32 + g * 8;
    short8 a[4];
#pragma unroll
    for (int fm = 0; fm < 4; ++fm)
      a[fm] = *(const short8*)(wqx_bf + (size_t)(wb + fm * 16 + lid) * 256 + kof);
#pragma unroll
    for (int fn = 0; fn < 4; ++fn) {
      short8 bb = frag_b(xl, fn * 16 + lid, kk, g);
#pragma unroll
      for (int fm = 0; fm < 4; ++fm)
        acc[fm][fn] = __builtin_amdgcn_mfma_f32_16x16x32_bf16(a[fm], bb, acc[fm][fn], 0, 0, 0);
    }
  }
  __syncthreads();  // x_lds reads done; buffer reused for t

  // t-phase: coefficients re-read from LDS per (fn,fm) to cap VGPR pressure
#pragma unroll
  for (int fn = 0; fn < 4; ++fn) {
    int l = fn * 16 + lid;
    float yv = yup_lds[l];
    float q[4][4];
    float d0 = 0.f, d1 = 0.f;
#pragma unroll
    for (int fm = 0; fm < 4; ++fm) {
      f32x4 wq4 = *(const f32x4*)&wqy_lds[wb + fm * 16 + g * 4];
      f32x4 ks4 = *(const f32x4*)&ksum_lds[wb + fm * 16 + g * 4];
#pragma unroll
      for (int r = 0; r < 4; ++r) {
        float v = acc[fm][fn][r] * (wq4[r] * yv);
        float qq = v > 0.f ? v + 1.f : __expf(v);   // elu(v)+1
        q[fm][r] = qq;
        if (fm < 2) d0 += qq * ks4[r]; else d1 += qq * ks4[r];
      }
    }
    // lanes {lid,lid+16,lid+32,lid+48} share same l -> head-sum over 32 c
    d0 += __shfl_xor(d0, 16); d0 += __shfl_xor(d0, 32);
    d1 += __shfl_xor(d1, 16); d1 += __shfl_xor(d1, 32);
    float zz0 = 1.f / (d0 + 1e-6f), zz1 = 1.f / (d1 + 1e-6f);
#pragma unroll
    for (int fm = 0; fm < 4; ++fm) {
      float zz = fm < 2 ? zz0 : zz1;
      f32x4 kv4 = *(const f32x4*)&kvs_lds[wb + fm * 16 + g * 4];
      ushort4v tw;
#pragma unroll
      for (int r = 0; r < 4; ++r) tw[r] = f2bf(q[fm][r] * kv4[r] * zz);
      int slot = (wave * 8 + fm * 2 + (g >> 1)) ^ swz(l);
      *(ushort4v*)(xl + (size_t)l * 512 + slot * 16 + (g & 1) * 8) = tw;
    }
  }
  __syncthreads();

  // GEMM2: out = w_out * t  (reuse acc)
#pragma unroll
  for (int i = 0; i < 4; ++i)
#pragma unroll
    for (int j = 0; j < 4; ++j) acc[i][j] = z4;
  for (int kk = 0; kk < 8; ++kk) {
    int kof = kk * 32 + g * 8;
    short8 a[4];
#pragma unroll
    for (int fm = 0; fm < 4; ++fm)
      a[fm] = *(const short8*)(wout_bf + (size_t)(wb + fm * 16 + lid) * 256 + kof);
#pragma unroll
    for (int fn = 0; fn < 4; ++fn) {
      short8 bb = frag_b(xl, fn * 16 + lid, kk, g);
#pragma unroll
      for (int fm = 0; fm < 4; ++fm)
        acc[fm][fn] = __builtin_amdgcn_mfma_f32_16x16x32_bf16(a[fm], bb, acc[fm][fn], 0, 0, 0);
    }
  }

  // epilogue
#pragma unroll
  for (int fm = 0; fm < 4; ++fm) {
#pragma unroll
    for (int r = 0; r < 4; ++r) {
      int o = wb + fm * 16 + g * 4 + r;
      float bo = bout_lds[o];
      size_t base = ((size_t)b * 256 + o) * LDIM + l0;
#pragma unroll
      for (int fn = 0; fn < 4; ++fn)
        out[base + fn * 16 + lid] = acc[fm][fn][r] + bo;
    }
  }
}

// ---------------- launch -------------------------------------------------------
extern "C" void kernel_launch(void* const* d_in, const int* in_sizes, int n_in,
                              void* d_out, int out_size, void* d_ws, size_t ws_size,
                              hipStream_t stream) {
  const float* x     = (const float*)d_in[0];
  const float* y     = (const float*)d_in[1];
  const float* wq_x  = (const float*)d_in[2];
  const float* wk_x  = (const float*)d_in[3];
  const float* wv    = (const float*)d_in[4];
  const float* wq_y  = (const float*)d_in[5];
  const float* wk_y  = (const float*)d_in[6];
  const float* w_out = (const float*)d_in[7];
  const float* b_out = (const float*)d_in[8];
  float* out = (float*)d_out;

  char* ws = (char*)d_ws;
  float* yup      = (float*)(ws + 0);         // 512 KB
  u16*   wqx_bf   = (u16*)(ws + 524288);      // 128 KB
  u16*   wkx_bf   = (u16*)(ws + 655360);      // 128 KB
  u16*   wout_bf  = (u16*)(ws + 786432);      // 128 KB
  u16*   wvsum_bf = (u16*)(ws + 917504);      // 8 KB
  float* ksum     = (float*)(ws + 925696);    // 8 KB
  float* kvs      = (float*)(ws + 933888);    // 8 KB
  float* part     = (float*)(ws + 942080);    // 2 MB

  k_prep<<<512, 256, 0, stream>>>(wq_x, wk_x, w_out, wv, y,
                                  wqx_bf, wkx_bf, wout_bf, wvsum_bf, yup);
  k_pass1<<<NB * NT1, 256, 0, stream>>>(x, wkx_bf, wvsum_bf, wk_y, yup, part);
  k_reduce<<<NB, 1024, 0, stream>>>(part, ksum, kvs);
  k_pass2<<<NB * NT2, 256, 0, stream>>>(x, wqx_bf, wout_bf, wq_y, yup,
                                        ksum, kvs, b_out, out);
}